// Round 10
// baseline (547.168 us; speedup 1.0000x reference)
//
#include <hip/hip_runtime.h>
#include <cstdint>

constexpr int H  = 16;
constexpr int D  = 64;
constexpr int DM = 1024;
constexpr int B  = 2;
constexpr int SL = 1024;
constexpr int CL = 512;
constexpr int KL = SL + CL;   // 1536
constexpr int SPAD = 1540;    // fp32 score row stride (words)
constexpr int EPAD = 1544;    // bf16 e-row stride (shorts)
constexpr size_t M1 = 1u << 20;

typedef short bf16x8  __attribute__((ext_vector_type(8)));
typedef float f32x4   __attribute__((ext_vector_type(4)));
typedef short short4v __attribute__((ext_vector_type(4)));

__device__ __forceinline__ short f2b(float f) {
    uint32_t u = __float_as_uint(f);
    u = (u + 0x7fffu + ((u >> 16) & 1u)) >> 16;   // RNE fp32 -> bf16
    return (short)u;
}

__device__ __forceinline__ bf16x8 ld8(const unsigned short* p) {
    return *reinterpret_cast<const bf16x8*>(p);
}

__device__ __forceinline__ void async16(const void* g, void* l) {
    __builtin_amdgcn_global_load_lds(
        (const __attribute__((address_space(1))) void*)g,
        (__attribute__((address_space(3))) void*)l,
        16, 0, 0);
}

__device__ __forceinline__ void nt_store4(f32x4 v, float* p) {
    __builtin_nontemporal_store(v, (f32x4*)p);    // ext-vector ptr: allowed
}

// ---------------- fp32 -> bf16 bulk convert --------------------------------
struct ConvSrc { const float* p[8]; };

__global__ __launch_bounds__(256)
void convert_kernel(ConvSrc srcs, unsigned short* __restrict__ dst)
{
    size_t i8 = (size_t)blockIdx.x * 256 + threadIdx.x;
    size_t e  = i8 * 8;                                   // < 9M
    int u = (int)(e >> 20);
    const float* s; size_t off;
    if (u < 2) { s = srcs.p[0]; off = e; }
    else       { s = srcs.p[u - 1]; off = e - ((size_t)u << 20); }
    float4 a = *reinterpret_cast<const float4*>(s + off);
    float4 b = *reinterpret_cast<const float4*>(s + off + 4);
    bf16x8 r;
    r[0]=f2b(a.x); r[1]=f2b(a.y); r[2]=f2b(a.z); r[3]=f2b(a.w);
    r[4]=f2b(b.x); r[5]=f2b(b.y); r[6]=f2b(b.z); r[7]=f2b(b.w);
    *reinterpret_cast<bf16x8*>(dst + e) = r;
}

// ---------------- BMx128-tile, BK=64, swizzled-LDS bf16 GEMM ---------------
// C[M,1024] = A[M,1024] @ W[1024,1024]^T + bias, scaled.
// 4 waves in 2x2 grid; wave tile (BM/2)x64. MFRAG = BM/32 A-frags per wave.
// LDS chunk map: chunk(row,g) = row*8 + (g ^ (row&7)); 16B chunks.
// MODE 0: bf16 -> [b, h, OUTLEN, 64] at row offset ROWOFF
// MODE 1: bf16 V^T -> [b, h, 64, KL] at col offset ROWOFF
// MODE 2: fp32 row-major [M, 1024] (nontemporal)
template<int BM, int MODE, int RPB_SHIFT, int OUTLEN, int ROWOFF>
__device__ __forceinline__ void gemm_body(
    const unsigned short* __restrict__ A,
    const unsigned short* __restrict__ W,
    const float* __restrict__ bias,
    void* __restrict__ outp, float scale,
    unsigned short* sA, unsigned short* sB, int by, int bx)
{
    constexpr int MFRAG = BM / 32;
    const int t   = threadIdx.x;
    const int l   = t & 63;
    const int wid = t >> 6;
    const int wr  = wid >> 1, wc = wid & 1;
    const int lr  = l & 15, lg = l >> 4;
    const int mbase = by * BM;
    const int nbase = bx * 128;

    f32x4 acc[MFRAG][4] = {};
    for (int k0 = 0; k0 < DM; k0 += 64) {
        #pragma unroll
        for (int i = 0; i < MFRAG; ++i) {          // A: BM*8 chunks
            int c = t + 256 * i;
            int row = c >> 3, gd = (c & 7) ^ (row & 7);
            async16(A + (size_t)(mbase + row) * DM + k0 + gd * 8, sA + c * 8);
        }
        #pragma unroll
        for (int i = 0; i < 4; ++i) {              // B: 1024 chunks
            int c = t + 256 * i;
            int row = c >> 3, gd = (c & 7) ^ (row & 7);
            async16(W + (size_t)(nbase + row) * DM + k0 + gd * 8, sB + c * 8);
        }
        __syncthreads();
        #pragma unroll
        for (int s = 0; s < 2; ++s) {
            bf16x8 af[MFRAG], bfr[4];
            #pragma unroll
            for (int i = 0; i < MFRAG; ++i) {
                int row = wr * (BM / 2) + i * 16 + lr;
                af[i] = ld8(sA + (row * 8 + ((s * 4 + lg) ^ (row & 7))) * 8);
            }
            #pragma unroll
            for (int j = 0; j < 4; ++j) {
                int row = wc * 64 + j * 16 + lr;
                bfr[j] = ld8(sB + (row * 8 + ((s * 4 + lg) ^ (row & 7))) * 8);
            }
            #pragma unroll
            for (int i = 0; i < MFRAG; ++i)
                #pragma unroll
                for (int j = 0; j < 4; ++j)
                    acc[i][j] = __builtin_amdgcn_mfma_f32_16x16x32_bf16(af[i], bfr[j], acc[i][j], 0, 0, 0);
        }
        __syncthreads();
    }

    #pragma unroll
    for (int mi = 0; mi < MFRAG; ++mi) {
        #pragma unroll
        for (int nj = 0; nj < 4; ++nj) {
            int n = nbase + wc * 64 + nj * 16 + lr;      // C/D col = lane&15
            float bi = bias[n];
            if (MODE == 1) {
                int m0 = mbase + wr * (BM / 2) + mi * 16 + lg * 4;
                int bb = m0 >> RPB_SHIFT;
                int s0 = m0 & ((1 << RPB_SHIFT) - 1);
                int hh = n >> 6, dd = n & 63;
                unsigned short* o = (unsigned short*)outp +
                    ((size_t)(bb * H + hh) * D + dd) * KL + ROWOFF + s0;
                short4v pk;
                #pragma unroll
                for (int r = 0; r < 4; ++r) pk[r] = f2b((acc[mi][nj][r] + bi) * scale);
                *reinterpret_cast<short4v*>(o) = pk;
            } else {
                #pragma unroll
                for (int r = 0; r < 4; ++r) {
                    int m = mbase + wr * (BM / 2) + mi * 16 + lg * 4 + r;
                    float v = (acc[mi][nj][r] + bi) * scale;
                    if (MODE == 0) {
                        int bb = m >> RPB_SHIFT;
                        int s  = m & ((1 << RPB_SHIFT) - 1);
                        int hh = n >> 6, dd = n & 63;
                        ((unsigned short*)outp)[((size_t)(bb * H + hh) * OUTLEN + ROWOFF + s) * D + dd]
                            = (unsigned short)f2b(v);
                    } else {
                        __builtin_nontemporal_store(v, (float*)outp + (size_t)m * DM + n);
                    }
                }
            }
        }
    }
}

// all 5 projections, BM=128: 3*(16x8) + 2*(8x8) = 512 blocks
__global__ __launch_bounds__(256, 2)
void proj_kernel(const unsigned short* __restrict__ Aself,
                 const unsigned short* __restrict__ Actx,
                 const unsigned short* __restrict__ Wq,
                 const unsigned short* __restrict__ Wks,
                 const unsigned short* __restrict__ Wvs,
                 const unsigned short* __restrict__ Wkc,
                 const unsigned short* __restrict__ Wvc,
                 const float* __restrict__ bq,  const float* __restrict__ bks,
                 const float* __restrict__ bvs, const float* __restrict__ bkc,
                 const float* __restrict__ bvc,
                 unsigned short* __restrict__ q_ws,
                 unsigned short* __restrict__ k_ws,
                 unsigned short* __restrict__ vT_ws)
{
    __shared__ unsigned short sA[128 * 64];   // 16 KB
    __shared__ unsigned short sB[128 * 64];   // 16 KB
    int bid = blockIdx.x;
    int z, by, bx;
    if (bid < 384) { z = bid >> 7; int r = bid & 127; by = r >> 3; bx = r & 7; }
    else { int tt = bid - 384; z = 3 + (tt >> 6); int r = tt & 63; by = r >> 3; bx = r & 7; }
    if (z == 0)
        gemm_body<128, 0, 10, SL, 0 >(Aself, Wq,  bq,  q_ws,  0.125f, sA, sB, by, bx);
    else if (z == 1)
        gemm_body<128, 0, 10, KL, 0 >(Aself, Wks, bks, k_ws,  1.0f,   sA, sB, by, bx);
    else if (z == 2)
        gemm_body<128, 1, 10, 0,  0 >(Aself, Wvs, bvs, vT_ws, 1.0f,   sA, sB, by, bx);
    else if (z == 3)
        gemm_body<128, 0, 9,  KL, SL>(Actx,  Wkc, bkc, k_ws,  1.0f,   sA, sB, by, bx);
    else
        gemm_body<128, 1, 9,  0,  SL>(Actx,  Wvc, bvc, vT_ws, 1.0f,   sA, sB, by, bx);
}

// output projection, BM=64: 32x8 = 256 blocks (1/CU)
__global__ __launch_bounds__(256, 2)
void out_proj_kernel(const unsigned short* __restrict__ ctx_bf,
                     const unsigned short* __restrict__ Wo,
                     const float* __restrict__ bo,
                     float* __restrict__ out0)
{
    __shared__ unsigned short sA[64 * 64];    // 8 KB
    __shared__ unsigned short sB[128 * 64];   // 16 KB
    gemm_body<64, 2, 10, 0, 0>(ctx_bf, Wo, bo, out0, 1.0f, sA, sB, blockIdx.y, blockIdx.x);
}

// ---------------- attention: LDS scores, wave-per-row softmax --------------
// 1024 threads = 16 waves; LDS ~149 KB -> 1 block/CU, 16 waves resident.
__global__ __launch_bounds__(1024, 4)
void attn_kernel(const unsigned short* __restrict__ q_ws,
                 const unsigned short* __restrict__ k_ws,
                 const unsigned short* __restrict__ vT_ws,
                 const int* __restrict__ self_mask,
                 const int* __restrict__ ctx_mask,
                 const float* __restrict__ ctx_bias,
                 float* __restrict__ attn_out,
                 float* __restrict__ top_out,
                 unsigned short* __restrict__ ctx_ws)
{
    __shared__ float s_scores[16 * SPAD];          // 98,560 B raw scores
    __shared__ unsigned short e_lds[16 * EPAD];    // 49,408 B normalized P bf16
    __shared__ float s_part[16 * 65];              // 4,160 B PV accum (padded)

    const int bid = blockIdx.x;
    const int bh  = bid & 31;        // bid%8 == bh%8 -> head pinned to one XCD
    const int qt  = bid >> 5;
    const int b   = bh >> 4;
    const int h   = bh & 15;
    const int t   = threadIdx.x;
    const int l   = t & 63;
    const int wid = t >> 6;          // 0..15
    const int lr  = l & 15;
    const int lg  = l >> 4;
    const int qrow0 = qt * 16;

    s_part[t] = 0.f;                 // 1024 of 1040
    if (t < 16) s_part[1024 + t] = 0.f;   // remaining 16 (was the NaN bug)

    const unsigned short* qb = q_ws + ((size_t)bh * SL + qrow0) * D;
    const unsigned short* kb = k_ws + (size_t)bh * KL * D;
    bf16x8 aq0 = ld8(qb + lr * D + lg * 8);
    bf16x8 aq1 = ld8(qb + lr * D + 32 + lg * 8);

    // ---- QK^T: 96 col-fragments, 6 per wave; raw scores -> LDS ----
    #pragma unroll
    for (int jj = 0; jj < 6; ++jj) {
        int j = wid * 6 + jj;
        int col = j * 16 + lr;
        bf16x8 bk0 = ld8(kb + (size_t)col * D + lg * 8);
        bf16x8 bk1 = ld8(kb + (size_t)col * D + 32 + lg * 8);
        f32x4 c = {};
        c = __builtin_amdgcn_mfma_f32_16x16x32_bf16(aq0, bk0, c, 0, 0, 0);
        c = __builtin_amdgcn_mfma_f32_16x16x32_bf16(aq1, bk1, c, 0, 0, 0);
        #pragma unroll
        for (int r = 0; r < 4; ++r)
            s_scores[(lg * 4 + r) * SPAD + col] = c[r];
    }
    __syncthreads();

    // ---- softmax: one wave per row, 6 float4 per lane ----
    {
        const int row = wid;
        const int qg  = qrow0 + row;
        const float cb = ctx_bias[0];
        const int4* sm4 = (const int4*)(self_mask + ((size_t)b * SL + qg) * SL);
        const int4* cm4 = (const int4*)(ctx_mask + (size_t)b * CL);
        float* srow = s_scores + row * SPAD;

        float4 ev[6];
        float mx = -3.0e38f;
        #pragma unroll
        for (int jj = 0; jj < 6; ++jj) {
            int c4 = l + jj * 64;            // float4 col, 0..383
            float4 s = *reinterpret_cast<const float4*>(srow + c4 * 4);
            if (jj < 4) {
                int4 m = sm4[c4];
                if (m.x) s.x = -1e30f;
                if (m.y) s.y = -1e30f;
                if (m.z) s.z = -1e30f;
                if (m.w) s.w = -1e30f;
            } else {
                int4 m = cm4[c4 - 256];
                s.x += cb; s.y += cb; s.z += cb; s.w += cb;
                if (m.x) s.x = -1e30f;
                if (m.y) s.y = -1e30f;
                if (m.z) s.z = -1e30f;
                if (m.w) s.w = -1e30f;
            }
            ev[jj] = s;
            mx = fmaxf(mx, fmaxf(fmaxf(s.x, s.y), fmaxf(s.z, s.w)));
        }
        #pragma unroll
        for (int o = 1; o < 64; o <<= 1) mx = fmaxf(mx, __shfl_xor(mx, o));

        float sum = 0.f, csum = 0.f;
        #pragma unroll
        for (int jj = 0; jj < 6; ++jj) {
            float4 s = ev[jj];
            float4 e;
            e.x = __expf(s.x - mx); e.y = __expf(s.y - mx);
            e.z = __expf(s.z - mx); e.w = __expf(s.w - mx);
            ev[jj] = e;
            float se = e.x + e.y + e.z + e.w;
            sum += se;
            if (jj >= 4) csum += se;
        }
        #pragma unroll
        for (int o = 1; o < 64; o <<= 1) { sum += __shfl_xor(sum, o); csum += __shfl_xor(csum, o); }
        float rden = 1.0f / sum;
        float rcs  = 1.0f / csum;

        float* arow = attn_out + ((size_t)bh * SL + qg) * KL;
        #pragma unroll
        for (int jj = 0; jj < 6; ++jj) {
            int c4 = l + jj * 64;
            float4 e = ev[jj];
            f32x4 w; w[0] = e.x * rden; w[1] = e.y * rden; w[2] = e.z * rden; w[3] = e.w * rden;
            nt_store4(w, arow + c4 * 4);
            short4v pk;
            pk[0] = f2b(w[0]); pk[1] = f2b(w[1]); pk[2] = f2b(w[2]); pk[3] = f2b(w[3]);
            *reinterpret_cast<short4v*>(e_lds + (size_t)row * EPAD + c4 * 4) = pk;
        }
        if (h == 0) {
            float* trow = top_out + ((size_t)b * SL + qg) * CL;
            #pragma unroll
            for (int jj = 4; jj < 6; ++jj) {
                int c4 = l + jj * 64;
                float4 e = ev[jj];
                f32x4 w; w[0] = e.x * rcs; w[1] = e.y * rcs; w[2] = e.z * rcs; w[3] = e.w * rcs;
                nt_store4(w, trow + (c4 - 256) * 4);
            }
        }
    }
    __syncthreads();

    // ---- PV: wave owns K-slice [wid*96, wid*96+96) ----
    const unsigned short* vb = vT_ws + (size_t)bh * D * KL;
    f32x4 accv[4] = {};
    #pragma unroll
    for (int ks = 0; ks < 3; ++ks) {
        int k0 = wid * 96 + ks * 32;
        bf16x8 ap = ld8(e_lds + (size_t)lr * EPAD + k0 + lg * 8);
        #pragma unroll
        for (int df = 0; df < 4; ++df) {
            bf16x8 bv = ld8(vb + (size_t)(df * 16 + lr) * KL + k0 + lg * 8);
            accv[df] = __builtin_amdgcn_mfma_f32_16x16x32_bf16(ap, bv, accv[df], 0, 0, 0);
        }
    }
    #pragma unroll
    for (int df = 0; df < 4; ++df)
        #pragma unroll
        for (int r = 0; r < 4; ++r)
            atomicAdd(&s_part[(lg * 4 + r) * 65 + df * 16 + lr], accv[df][r]);
    __syncthreads();

    {
        int srow = t >> 6, dd = t & 63;
        ctx_ws[((size_t)b * SL + qrow0 + srow) * DM + h * D + dd]
            = (unsigned short)f2b(s_part[srow * 65 + dd]);
    }
}

extern "C" void kernel_launch(void* const* d_in, const int* in_sizes, int n_in,
                              void* d_out, int out_size, void* d_ws, size_t ws_size,
                              hipStream_t stream)
{
    const float* self_kvq = (const float*)d_in[0];
    const float* ctx_kv   = (const float*)d_in[1];
    const int*   self_mask= (const int*)d_in[2];
    const int*   ctx_mask = (const int*)d_in[3];
    const float* Wq  = (const float*)d_in[4];
    const float* bq  = (const float*)d_in[5];
    const float* Wks = (const float*)d_in[6];
    const float* bks = (const float*)d_in[7];
    const float* Wvs = (const float*)d_in[8];
    const float* bvs = (const float*)d_in[9];
    const float* Wkc = (const float*)d_in[10];
    const float* bkc = (const float*)d_in[11];
    const float* Wvc = (const float*)d_in[12];
    const float* bvc = (const float*)d_in[13];
    const float* ctx_bias = (const float*)d_in[14];
    const float* Wo  = (const float*)d_in[15];
    const float* bo  = (const float*)d_in[16];

    float* out0     = (float*)d_out;                       // (B, SL, DM)
    float* out_top  = out0 + (size_t)B * SL * DM;          // (B, SL, CL)
    float* out_attn = out_top + (size_t)B * SL * CL;       // (B, H, SL, KL)

    unsigned short* wsp  = (unsigned short*)d_ws;
    unsigned short* Abf_self = wsp + 0 * M1;   // 2M (aliased by ctx_ws later)
    unsigned short* Abf_ctx  = wsp + 2 * M1;
    unsigned short* Wq_b     = wsp + 3 * M1;
    unsigned short* Wks_b    = wsp + 4 * M1;
    unsigned short* Wvs_b    = wsp + 5 * M1;
    unsigned short* Wkc_b    = wsp + 6 * M1;
    unsigned short* Wvc_b    = wsp + 7 * M1;
    unsigned short* Wo_b     = wsp + 8 * M1;
    unsigned short* q_ws     = wsp + 9 * M1;   // [B,H,SL,64]
    unsigned short* k_ws     = wsp + 11 * M1;  // [B,H,KL,64]
    unsigned short* vT_ws    = wsp + 14 * M1;  // [B,H,64,KL]
    unsigned short* ctx_ws   = wsp + 0;        // [B*SL, DM] (alias Abf_self)

    ConvSrc cs;
    cs.p[0] = self_kvq; cs.p[1] = ctx_kv;
    cs.p[2] = Wq; cs.p[3] = Wks; cs.p[4] = Wvs;
    cs.p[5] = Wkc; cs.p[6] = Wvc; cs.p[7] = Wo;
    convert_kernel<<<4608, 256, 0, stream>>>(cs, wsp);

    proj_kernel<<<dim3(512), 256, 0, stream>>>(
        Abf_self, Abf_ctx, Wq_b, Wks_b, Wvs_b, Wkc_b, Wvc_b,
        bq, bks, bvs, bkc, bvc, q_ws, k_ws, vT_ws);

    attn_kernel<<<dim3(2048), 1024, 0, stream>>>(q_ws, k_ws, vT_ws,
        self_mask, ctx_mask, ctx_bias, out_attn, out_top, ctx_ws);

    out_proj_kernel<<<dim3(8, 32), 256, 0, stream>>>(ctx_ws, Wo_b, bo, out0);
}